// Round 4
// baseline (1396.825 us; speedup 1.0000x reference)
//
#include <hip/hip_runtime.h>
#include <math.h>

#define NNODES 100000
#define NEDGES 3200000
#define F 128
#define NPB 512
#define NB ((NNODES + NPB - 1) / NPB)   // 196 buckets
#define CAP 20480                        // slots per bucket (mean 16326, 32 sigma margin)
#define T2 8192
#define NSLICE 8                         // feature slices (16 feats = 32B per row each)

typedef __attribute__((ext_vector_type(8))) short short8;
typedef __attribute__((ext_vector_type(4))) float f32x4;
typedef __attribute__((ext_vector_type(4))) unsigned uintx4;   // nontemporal-builtin-compatible

__device__ __forceinline__ unsigned short f2bf(float f) {
    unsigned u = __float_as_uint(f);
    unsigned r = u + 0x7fff + ((u >> 16) & 1);
    return (unsigned short)(r >> 16);
}
__device__ __forceinline__ float bflo(unsigned u) { return __uint_as_float(u << 16); }
__device__ __forceinline__ float bfhi(unsigned u) { return __uint_as_float(u & 0xffff0000u); }

// ---------------- cursor init (CAP-strided bucket bases) ----------------

__global__ void init_cursors_kernel(int* __restrict__ dcur, int* __restrict__ scur) {
    int b = blockIdx.x * 256 + threadIdx.x;
    if (b < NB) { dcur[b] = b * CAP; scur[b] = b * CAP; }
}

// ---------------- dual binning: one edge read -> dst-keyed + src-keyed bins ----------------

__global__ __launch_bounds__(256) void dual_bin_kernel(const int* __restrict__ src,
                                                       const int* __restrict__ dst,
                                                       int* __restrict__ dcur,
                                                       int* __restrict__ scur,
                                                       unsigned* __restrict__ epk,
                                                       unsigned short* __restrict__ esl) {
    __shared__ unsigned pk[T2];
    __shared__ unsigned short sl[T2];
    __shared__ unsigned char db[T2], sb[T2];
    __shared__ int dh[NB], dbase[NB], dlc[NB];
    __shared__ int sh[NB], sbase[NB], slc[NB];
    int t = threadIdx.x;
    for (int i = t; i < NB; i += 256) { dh[i] = 0; dlc[i] = 0; sh[i] = 0; slc[i] = 0; }
    __syncthreads();
    int e0 = blockIdx.x * T2;
    int n = min(T2, NEDGES - e0);
    for (int i = t; i < n; i += 256) {
        int s = src[e0 + i], d = dst[e0 + i];
        int bd = d >> 9, bs = s >> 9;
        pk[i] = (unsigned)s | ((unsigned)(d & 511) << 17);
        sl[i] = (unsigned short)(s & 511);
        db[i] = (unsigned char)bd;
        sb[i] = (unsigned char)bs;
        atomicAdd(&dh[bd], 1);
        atomicAdd(&sh[bs], 1);
    }
    __syncthreads();
    for (int b = t; b < NB; b += 256) {
        if (dh[b]) dbase[b] = atomicAdd(&dcur[b], dh[b]);
        if (sh[b]) sbase[b] = atomicAdd(&scur[b], sh[b]);
    }
    __syncthreads();
    for (int i = t; i < n; i += 256) {
        int b = db[i];
        epk[dbase[b] + atomicAdd(&dlc[b], 1)] = pk[i];
    }
    for (int i = t; i < n; i += 256) {
        int b = sb[i];
        esl[sbase[b] + atomicAdd(&slc[b], 1)] = sl[i];
    }
}

// ---------------- out-degree -> out_norm (per-bucket LDS histogram) ----------------

__global__ __launch_bounds__(512) void src_hist_kernel(const unsigned short* __restrict__ esl,
                                                       const int* __restrict__ scur,
                                                       float* __restrict__ out_norm) {
    __shared__ int cnt[NPB];
    int t = threadIdx.x, b = blockIdx.x;
    cnt[t] = 0;
    __syncthreads();
    int e0 = b * CAP, e1 = scur[b];
    for (int i = e0 + t; i < e1; i += 512) atomicAdd(&cnt[esl[i]], 1);
    __syncthreads();
    int node = b * NPB + t;
    if (node < NNODES) out_norm[node] = rsqrtf((float)max(cnt[t], 1));
}

// ---------------- per-bucket fine CSR + in_norm (all-LDS cursors) ----------------

__global__ __launch_bounds__(512) void bucket_csr_kernel(const unsigned* __restrict__ epk,
                                                         const int* __restrict__ dcur,
                                                         int2* __restrict__ row_span,
                                                         float* __restrict__ in_norm,
                                                         int* __restrict__ csr_src) {
    __shared__ int hist[NPB], off[NPB], lcur[NPB];
    int t = threadIdx.x, b = blockIdx.x;
    hist[t] = 0; lcur[t] = 0;
    __syncthreads();
    int e0 = b * CAP, e1 = dcur[b];
    for (int i = e0 + t; i < e1; i += 512)
        atomicAdd(&hist[epk[i] >> 17], 1);
    __syncthreads();
    int h = hist[t];
    off[t] = h;
    __syncthreads();
    for (int d = 1; d < NPB; d <<= 1) {
        int u = (t >= d) ? off[t - d] : 0;
        __syncthreads();
        off[t] += u;
        __syncthreads();
    }
    int excl = off[t] - h;
    int node = b * NPB + t;
    if (node < NNODES) {
        row_span[node] = make_int2(e0 + excl, e0 + excl + h);
        in_norm[node] = rsqrtf((float)max(h, 1));
    }
    __syncthreads();
    off[t] = excl;
    __syncthreads();
    for (int i = e0 + t; i < e1; i += 512) {
        unsigned p = epk[i];
        int dl = p >> 17;
        csr_src[e0 + off[dl] + atomicAdd(&lcur[dl], 1)] = (int)(p & 0x1FFFF);
    }
}

// ---------------- x * out_norm -> bf16, SLICE-MAJOR: hs[slice][node][16 feats] ----------------
// slice s holds feats [s*16, s*16+16) of every node as a dense 3.2 MB array (fits one XCD L2)

__global__ __launch_bounds__(256) void scale_to_bf16_kernel(const float* __restrict__ x,
                                                            const float* __restrict__ out_norm,
                                                            uint2* __restrict__ hs) {
    int tid = blockIdx.x * 256 + threadIdx.x;
    if (tid >= NNODES * 32) return;
    int row = tid >> 5, q = tid & 31;          // q = 4-feat group, feats q*4..q*4+3
    float nrm = out_norm[row];
    float4 v = *(const float4*)(x + (size_t)row * F + q * 4);
    uint2 o;
    o.x = (unsigned)f2bf(v.x * nrm) | ((unsigned)f2bf(v.y * nrm) << 16);
    o.y = (unsigned)f2bf(v.z * nrm) | ((unsigned)f2bf(v.w * nrm) << 16);
    // slice = q>>2 (16 feats = 4 uint2), within-row uint2 index = q&3
    hs[((size_t)(q >> 2) * NNODES + row) * 4 + (q & 3)] = o;
}

// ---------------- pack all 4 weight matrices into MFMA B-fragments ----------------
// Bp[(c*4+s)*64+lane] = W[s*32+(lane>>4)*8+j][c*16+(lane&15)]

__global__ void pack_all_kernel(const float* __restrict__ W1, const float* __restrict__ W2,
                                const float* __restrict__ Wm1, const float* __restrict__ Wm2,
                                short8* __restrict__ Wp) {
    int idx = blockIdx.x * 256 + threadIdx.x;
    if (idx >= 7168) return;
    const float* W; int ncol, base;
    if (idx < 2048)      { W = W1;  ncol = 128; base = 0; }
    else if (idx < 4096) { W = W2;  ncol = 128; base = 2048; }
    else if (idx < 6144) { W = Wm1; ncol = 128; base = 4096; }
    else                 { W = Wm2; ncol = 64;  base = 6144; }
    int li = idx - base;
    int lane = li & 63, s = (li >> 6) & 3, c = li >> 8;
    int nn = c * 16 + (lane & 15);
    int k0 = s * 32 + (lane >> 4) * 8;
    short8 v;
#pragma unroll
    for (int j = 0; j < 8; j++) v[j] = (short)f2bf(W[(size_t)(k0 + j) * ncol + nn]);
    Wp[idx] = v;
}

// ---------------- aggregation: XCD-sliced gather, ONE LANE per node-slice ----------------
// slice = blockIdx&7 -> round-robin block->XCD mapping pins each 3.2MB slice to one XCD's L2.
// Lane owns the full 32B slice of one node: 16 fp32 accumulators, no cross-lane reduction,
// no shuffles (round-2 killer: 12.8M ds_bpermute ~ 100us on the DS pipe), no masking.
// csr reads are per-lane linear streams (non-temporal: don't evict the slice from L2).

__global__ __launch_bounds__(256) void aggregate_kernel(const uintx4* __restrict__ hsv4,
                                                        const int2* __restrict__ row_span,
                                                        const int* __restrict__ csr_src,
                                                        const float* __restrict__ in_norm,
                                                        uintx4* __restrict__ outv4) {
    int slice = blockIdx.x & 7;
    int node = (blockIdx.x >> 3) * 256 + threadIdx.x;
    if (node >= NNODES) return;
    const uintx4* base = hsv4 + (size_t)slice * (NNODES * 2);
    int2 sp = row_span[node];
    float s0 = 0.f, s1 = 0.f, s2 = 0.f, s3 = 0.f, s4 = 0.f, s5 = 0.f, s6 = 0.f, s7 = 0.f,
          s8 = 0.f, s9 = 0.f, s10 = 0.f, s11 = 0.f, s12 = 0.f, s13 = 0.f, s14 = 0.f, s15 = 0.f;
    for (int e = sp.x; e < sp.y; ++e) {
        unsigned r = (unsigned)__builtin_nontemporal_load(csr_src + e);
        uintx4 a = hsv4[(size_t)slice * (NNODES * 2) + (size_t)r * 2];
        uintx4 b = base[(size_t)r * 2 + 1];
        s0 += bflo(a.x);  s1 += bfhi(a.x);
        s2 += bflo(a.y);  s3 += bfhi(a.y);
        s4 += bflo(a.z);  s5 += bfhi(a.z);
        s6 += bflo(a.w);  s7 += bfhi(a.w);
        s8 += bflo(b.x);  s9 += bfhi(b.x);
        s10 += bflo(b.y); s11 += bfhi(b.y);
        s12 += bflo(b.z); s13 += bfhi(b.z);
        s14 += bflo(b.w); s15 += bfhi(b.w);
    }
    float inn = in_norm[node];
    uintx4 o0, o1;
    o0.x = (unsigned)f2bf(s0 * inn)  | ((unsigned)f2bf(s1 * inn) << 16);
    o0.y = (unsigned)f2bf(s2 * inn)  | ((unsigned)f2bf(s3 * inn) << 16);
    o0.z = (unsigned)f2bf(s4 * inn)  | ((unsigned)f2bf(s5 * inn) << 16);
    o0.w = (unsigned)f2bf(s6 * inn)  | ((unsigned)f2bf(s7 * inn) << 16);
    o1.x = (unsigned)f2bf(s8 * inn)  | ((unsigned)f2bf(s9 * inn) << 16);
    o1.y = (unsigned)f2bf(s10 * inn) | ((unsigned)f2bf(s11 * inn) << 16);
    o1.z = (unsigned)f2bf(s12 * inn) | ((unsigned)f2bf(s13 * inn) << 16);
    o1.w = (unsigned)f2bf(s14 * inn) | ((unsigned)f2bf(s15 * inn) << 16);
    size_t ob = ((size_t)slice * NNODES + node) * 2;
    __builtin_nontemporal_store(o0, outv4 + ob);
    __builtin_nontemporal_store(o1, outv4 + ob + 1);
}

// ---------------- MFMA GEMM (conv layers): relu(A@W+b), optional *out_norm ----------------
// A and Cout are SLICE-MAJOR ushort: buf[(slice*NNODES + row)*16 + f], f in [0,16)

template <int SCALE>
__global__ __launch_bounds__(256) void gemm_mfma_kernel(const unsigned short* __restrict__ A,
                                                        const short8* __restrict__ Bp,
                                                        const float* __restrict__ bias,
                                                        const float* __restrict__ out_norm,
                                                        unsigned short* __restrict__ Cout, int nrows) {
    int w = threadIdx.x >> 6, lane = threadIdx.x & 63;
    int m = lane & 15, quad = lane >> 4;
    int row0 = blockIdx.x * 64 + w * 16;

    int arow = min(row0 + m, nrows - 1);
    short8 afrag[4];
#pragma unroll
    for (int s = 0; s < 4; s++)
        afrag[s] = *(const short8*)(A + ((size_t)(2 * s + (quad >> 1)) * NNODES + arow) * 16 + (quad & 1) * 8);

    int baseRow = row0 + quad * 4;
    float nrm[4];
    if (SCALE) {
#pragma unroll
        for (int r = 0; r < 4; r++) nrm[r] = out_norm[min(baseRow + r, nrows - 1)];
    }

#pragma unroll
    for (int c = 0; c < 8; c++) {
        f32x4 acc = {0.f, 0.f, 0.f, 0.f};
#pragma unroll
        for (int s = 0; s < 4; s++) {
            short8 b = Bp[(c * 4 + s) * 64 + lane];
            acc = __builtin_amdgcn_mfma_f32_16x16x32_bf16(afrag[s], b, acc, 0, 0, 0);
        }
        float bc = bias[c * 16 + m];
#pragma unroll
        for (int r = 0; r < 4; r++) {
            int row = baseRow + r;
            if (row < nrows) {
                float v = fmaxf(acc[r] + bc, 0.f);
                if (SCALE) v *= nrm[r];
                // feat = c*16+m -> slice = c, within = m
                Cout[((size_t)c * NNODES + row) * 16 + m] = f2bf(v);
            }
        }
    }
}

// ---------------- fused MLP head: sigmoid(relu(A@Wm1+bm1)@Wm2+bm2) ----------------
// A is SLICE-MAJOR; output row-major f32

__global__ __launch_bounds__(256) void mlp_fused_kernel(const unsigned short* __restrict__ A,
                                                        const short8* __restrict__ Bp1,
                                                        const float* __restrict__ bm1,
                                                        const short8* __restrict__ Bp2,
                                                        const float* __restrict__ bm2,
                                                        float* __restrict__ out, int nrows) {
    __shared__ unsigned short h3[4][16][136];   // +8 pad: break bank conflicts
    int w = threadIdx.x >> 6, lane = threadIdx.x & 63;
    int m = lane & 15, quad = lane >> 4;
    int row0 = blockIdx.x * 64 + w * 16;

    int arow = min(row0 + m, nrows - 1);
    short8 afrag[4];
#pragma unroll
    for (int s = 0; s < 4; s++)
        afrag[s] = *(const short8*)(A + ((size_t)(2 * s + (quad >> 1)) * NNODES + arow) * 16 + (quad & 1) * 8);

#pragma unroll
    for (int c = 0; c < 8; c++) {
        f32x4 acc = {0.f, 0.f, 0.f, 0.f};
#pragma unroll
        for (int s = 0; s < 4; s++) {
            short8 b = Bp1[(c * 4 + s) * 64 + lane];
            acc = __builtin_amdgcn_mfma_f32_16x16x32_bf16(afrag[s], b, acc, 0, 0, 0);
        }
        float bc = bm1[c * 16 + m];
#pragma unroll
        for (int r = 0; r < 4; r++)
            h3[w][quad * 4 + r][c * 16 + m] = f2bf(fmaxf(acc[r] + bc, 0.f));
    }
    __syncthreads();

    short8 a2[4];
#pragma unroll
    for (int s = 0; s < 4; s++)
        a2[s] = *(const short8*)(&h3[w][m][s * 32 + quad * 8]);

    int baseRow = row0 + quad * 4;
#pragma unroll
    for (int c2 = 0; c2 < 4; c2++) {
        f32x4 acc = {0.f, 0.f, 0.f, 0.f};
#pragma unroll
        for (int s = 0; s < 4; s++) {
            short8 b = Bp2[(c2 * 4 + s) * 64 + lane];
            acc = __builtin_amdgcn_mfma_f32_16x16x32_bf16(a2[s], b, acc, 0, 0, 0);
        }
        float bc = bm2[c2 * 16 + m];
#pragma unroll
        for (int r = 0; r < 4; r++) {
            int row = baseRow + r;
            if (row < nrows)
                out[(size_t)row * 64 + c2 * 16 + m] = 1.f / (1.f + __expf(-(acc[r] + bc)));
        }
    }
}

// ---------------- launch ----------------

extern "C" void kernel_launch(void* const* d_in, const int* in_sizes, int n_in,
                              void* d_out, int out_size, void* d_ws, size_t ws_size,
                              hipStream_t stream) {
    const float* x   = (const float*)d_in[0];
    const int* src   = (const int*)d_in[1];
    const int* dst   = (const int*)d_in[2];
    const float* W1  = (const float*)d_in[3];
    const float* b1  = (const float*)d_in[4];
    const float* W2  = (const float*)d_in[5];
    const float* b2  = (const float*)d_in[6];
    const float* Wm1 = (const float*)d_in[7];
    const float* bm1 = (const float*)d_in[8];
    const float* Wm2 = (const float*)d_in[9];
    const float* bm2 = (const float*)d_in[10];
    float* out = (float*)d_out;

    char* w = (char*)d_ws;
    int* dcur          = (int*)w;   w += (size_t)(NB + 4) * 4;
    int* scur          = (int*)w;   w += (size_t)(NB + 4) * 4;
    float* out_norm    = (float*)w; w += (size_t)NNODES * 4;
    float* in_norm     = (float*)w; w += (size_t)NNODES * 4;
    int2* row_span     = (int2*)w;  w += (size_t)NNODES * 8;
    int* csr_src       = (int*)w;   w += (size_t)NB * CAP * 4;
    unsigned* epk      = (unsigned*)w; w += (size_t)NB * CAP * 4;
    unsigned short* esl= (unsigned short*)w; w += (size_t)NB * CAP * 2;
    short8* Wp         = (short8*)w; w += (size_t)7168 * 16;
    unsigned* bufX     = (unsigned*)w; w += (size_t)NNODES * 64 * 4;
    unsigned* bufY     = (unsigned*)w; w += (size_t)NNODES * 64 * 4;

    init_cursors_kernel<<<1, 256, 0, stream>>>(dcur, scur);
    dual_bin_kernel<<<(NEDGES + T2 - 1) / T2, 256, 0, stream>>>(src, dst, dcur, scur, epk, esl);
    src_hist_kernel<<<NB, 512, 0, stream>>>(esl, scur, out_norm);
    bucket_csr_kernel<<<NB, 512, 0, stream>>>(epk, dcur, row_span, in_norm, csr_src);
    scale_to_bf16_kernel<<<(NNODES * 32 + 255) / 256, 256, 0, stream>>>(x, out_norm, (uint2*)bufX);
    pack_all_kernel<<<28, 256, 0, stream>>>(W1, W2, Wm1, Wm2, Wp);

    const int aggGrid = ((NNODES + 255) / 256) * NSLICE;   // 391 node-groups x 8 slices = 3128 blocks
    const int gemmGrid = (NNODES + 63) / 64;

    aggregate_kernel<<<aggGrid, 256, 0, stream>>>((const uintx4*)bufX, row_span, csr_src, in_norm, (uintx4*)bufY);
    gemm_mfma_kernel<1><<<gemmGrid, 256, 0, stream>>>((const unsigned short*)bufY, Wp, b1, out_norm,
                                                      (unsigned short*)bufX, NNODES);
    aggregate_kernel<<<aggGrid, 256, 0, stream>>>((const uintx4*)bufX, row_span, csr_src, in_norm, (uintx4*)bufY);
    gemm_mfma_kernel<0><<<gemmGrid, 256, 0, stream>>>((const unsigned short*)bufY, Wp + 2048, b2, out_norm,
                                                      (unsigned short*)bufX, NNODES);
    mlp_fused_kernel<<<gemmGrid, 256, 0, stream>>>((const unsigned short*)bufX, Wp + 4096, bm1,
                                                   Wp + 6144, bm2, out, NNODES);
}

// Round 5
// 674.773 us; speedup vs baseline: 2.0701x; 2.0701x over previous
//
#include <hip/hip_runtime.h>
#include <math.h>

#define NNODES 100000
#define NEDGES 3200000
#define F 128
#define NPB 512
#define NB ((NNODES + NPB - 1) / NPB)   // 196 buckets
#define CAP 20480                        // slots per bucket (mean 16326, 32 sigma margin)
#define T2 8192
#define NSLICE 8                         // feature slices (16 feats = 32B per row each)

typedef __attribute__((ext_vector_type(8))) short short8;
typedef __attribute__((ext_vector_type(4))) float f32x4;

__device__ __forceinline__ unsigned short f2bf(float f) {
    unsigned u = __float_as_uint(f);
    unsigned r = u + 0x7fff + ((u >> 16) & 1);
    return (unsigned short)(r >> 16);
}
__device__ __forceinline__ float bflo(unsigned u) { return __uint_as_float(u << 16); }
__device__ __forceinline__ float bfhi(unsigned u) { return __uint_as_float(u & 0xffff0000u); }

// ---------------- cursor init (CAP-strided bucket bases) ----------------

__global__ void init_cursors_kernel(int* __restrict__ dcur, int* __restrict__ scur) {
    int b = blockIdx.x * 256 + threadIdx.x;
    if (b < NB) { dcur[b] = b * CAP; scur[b] = b * CAP; }
}

// ---------------- dual binning: one edge read -> dst-keyed + src-keyed bins ----------------

__global__ __launch_bounds__(256) void dual_bin_kernel(const int* __restrict__ src,
                                                       const int* __restrict__ dst,
                                                       int* __restrict__ dcur,
                                                       int* __restrict__ scur,
                                                       unsigned* __restrict__ epk,
                                                       unsigned short* __restrict__ esl) {
    __shared__ unsigned pk[T2];
    __shared__ unsigned short sl[T2];
    __shared__ unsigned char db[T2], sb[T2];
    __shared__ int dh[NB], dbase[NB], dlc[NB];
    __shared__ int sh[NB], sbase[NB], slc[NB];
    int t = threadIdx.x;
    for (int i = t; i < NB; i += 256) { dh[i] = 0; dlc[i] = 0; sh[i] = 0; slc[i] = 0; }
    __syncthreads();
    int e0 = blockIdx.x * T2;
    int n = min(T2, NEDGES - e0);
    for (int i = t; i < n; i += 256) {
        int s = src[e0 + i], d = dst[e0 + i];
        int bd = d >> 9, bs = s >> 9;
        pk[i] = (unsigned)s | ((unsigned)(d & 511) << 17);
        sl[i] = (unsigned short)(s & 511);
        db[i] = (unsigned char)bd;
        sb[i] = (unsigned char)bs;
        atomicAdd(&dh[bd], 1);
        atomicAdd(&sh[bs], 1);
    }
    __syncthreads();
    for (int b = t; b < NB; b += 256) {
        if (dh[b]) dbase[b] = atomicAdd(&dcur[b], dh[b]);
        if (sh[b]) sbase[b] = atomicAdd(&scur[b], sh[b]);
    }
    __syncthreads();
    for (int i = t; i < n; i += 256) {
        int b = db[i];
        epk[dbase[b] + atomicAdd(&dlc[b], 1)] = pk[i];
    }
    for (int i = t; i < n; i += 256) {
        int b = sb[i];
        esl[sbase[b] + atomicAdd(&slc[b], 1)] = sl[i];
    }
}

// ---------------- out-degree -> out_norm (per-bucket LDS histogram) ----------------

__global__ __launch_bounds__(512) void src_hist_kernel(const unsigned short* __restrict__ esl,
                                                       const int* __restrict__ scur,
                                                       float* __restrict__ out_norm) {
    __shared__ int cnt[NPB];
    int t = threadIdx.x, b = blockIdx.x;
    cnt[t] = 0;
    __syncthreads();
    int e0 = b * CAP, e1 = scur[b];
    for (int i = e0 + t; i < e1; i += 512) atomicAdd(&cnt[esl[i]], 1);
    __syncthreads();
    int node = b * NPB + t;
    if (node < NNODES) out_norm[node] = rsqrtf((float)max(cnt[t], 1));
}

// ---------------- per-bucket fine CSR + in_norm (all-LDS cursors) ----------------

__global__ __launch_bounds__(512) void bucket_csr_kernel(const unsigned* __restrict__ epk,
                                                         const int* __restrict__ dcur,
                                                         int2* __restrict__ row_span,
                                                         float* __restrict__ in_norm,
                                                         int* __restrict__ csr_src) {
    __shared__ int hist[NPB], off[NPB], lcur[NPB];
    int t = threadIdx.x, b = blockIdx.x;
    hist[t] = 0; lcur[t] = 0;
    __syncthreads();
    int e0 = b * CAP, e1 = dcur[b];
    for (int i = e0 + t; i < e1; i += 512)
        atomicAdd(&hist[epk[i] >> 17], 1);
    __syncthreads();
    int h = hist[t];
    off[t] = h;
    __syncthreads();
    for (int d = 1; d < NPB; d <<= 1) {
        int u = (t >= d) ? off[t - d] : 0;
        __syncthreads();
        off[t] += u;
        __syncthreads();
    }
    int excl = off[t] - h;
    int node = b * NPB + t;
    if (node < NNODES) {
        row_span[node] = make_int2(e0 + excl, e0 + excl + h);
        in_norm[node] = rsqrtf((float)max(h, 1));
    }
    __syncthreads();
    off[t] = excl;
    __syncthreads();
    for (int i = e0 + t; i < e1; i += 512) {
        unsigned p = epk[i];
        int dl = p >> 17;
        csr_src[e0 + off[dl] + atomicAdd(&lcur[dl], 1)] = (int)(p & 0x1FFFF);
    }
}

// ---------------- x * out_norm -> bf16, SLICE-MAJOR: hs[slice][node][16 feats] ----------------
// slice s holds feats [s*16, s*16+16) of every node as a dense 3.2 MB array (fits one XCD L2)

__global__ __launch_bounds__(256) void scale_to_bf16_kernel(const float* __restrict__ x,
                                                            const float* __restrict__ out_norm,
                                                            uint2* __restrict__ hs) {
    int tid = blockIdx.x * 256 + threadIdx.x;
    if (tid >= NNODES * 32) return;
    int row = tid >> 5, q = tid & 31;          // q = 4-feat group, feats q*4..q*4+3
    float nrm = out_norm[row];
    float4 v = *(const float4*)(x + (size_t)row * F + q * 4);
    uint2 o;
    o.x = (unsigned)f2bf(v.x * nrm) | ((unsigned)f2bf(v.y * nrm) << 16);
    o.y = (unsigned)f2bf(v.z * nrm) | ((unsigned)f2bf(v.w * nrm) << 16);
    // slice = q>>2 (16 feats = 4 uint2), within-row uint2 index = q&3
    hs[((size_t)(q >> 2) * NNODES + row) * 4 + (q & 3)] = o;
}

// ---------------- pack all 4 weight matrices into MFMA B-fragments ----------------
// Bp[(c*4+s)*64+lane] = W[s*32+(lane>>4)*8+j][c*16+(lane&15)]

__global__ void pack_all_kernel(const float* __restrict__ W1, const float* __restrict__ W2,
                                const float* __restrict__ Wm1, const float* __restrict__ Wm2,
                                short8* __restrict__ Wp) {
    int idx = blockIdx.x * 256 + threadIdx.x;
    if (idx >= 7168) return;
    const float* W; int ncol, base;
    if (idx < 2048)      { W = W1;  ncol = 128; base = 0; }
    else if (idx < 4096) { W = W2;  ncol = 128; base = 2048; }
    else if (idx < 6144) { W = Wm1; ncol = 128; base = 4096; }
    else                 { W = Wm2; ncol = 64;  base = 6144; }
    int li = idx - base;
    int lane = li & 63, s = (li >> 6) & 3, c = li >> 8;
    int nn = c * 16 + (lane & 15);
    int k0 = s * 32 + (lane >> 4) * 8;
    short8 v;
#pragma unroll
    for (int j = 0; j < 8; j++) v[j] = (short)f2bf(W[(size_t)(k0 + j) * ncol + nn]);
    Wp[idx] = v;
}

// ---------------- aggregation: XCD-sliced, 8 nodes/wave, lane=(node, feat-pair) ----------------
// slice = blockIdx&7 -> round-robin block->XCD mapping pins each 3.2MB slice to one XCD's L2.
// Lane l: node-subgroup l>>3 (8 CONSECUTIVE nodes/wave -> contiguous csr window, L1-resident),
// feat-pair l&7 (uint = 2 bf16). Subgroup's 8 lanes read same csr entry (broadcast) and one
// contiguous 32B row-slice (wave-coherent gather: r1-2 pattern -> FETCH 70MB). Lane exclusively
// owns its (node, feat-pair) accumulator -> ZERO shuffles (r2 killer), ZERO masking (divergent
// exec-masked loop), coalesced 256B store.

__global__ __launch_bounds__(256) void aggregate_kernel(const unsigned* __restrict__ hsu,
                                                        const int2* __restrict__ row_span,
                                                        const int* __restrict__ csr_src,
                                                        const float* __restrict__ in_norm,
                                                        unsigned* __restrict__ outu) {
    int slice = blockIdx.x & 7;
    int wave = threadIdx.x >> 6;
    int lane = threadIdx.x & 63;
    int sub  = lane >> 3;                       // node within group of 8
    int fp   = lane & 7;                        // uint index within 32B row-slice
    int node = (blockIdx.x >> 3) * 32 + wave * 8 + sub;   // 3125*32 = 100000 exact
    const unsigned* base = hsu + (size_t)slice * ((size_t)NNODES * 8);
    int2 sp = row_span[node];
    int e = sp.x, end = sp.y;
    float sx = 0.f, sy = 0.f;
    for (; e + 1 < end; e += 2) {               // 2 independent gather chains in flight
        unsigned r0 = (unsigned)csr_src[e];
        unsigned r1 = (unsigned)csr_src[e + 1];
        unsigned v0 = base[(r0 << 3) | fp];
        unsigned v1 = base[(r1 << 3) | fp];
        sx += bflo(v0) + bflo(v1);
        sy += bfhi(v0) + bfhi(v1);
    }
    if (e < end) {
        unsigned v = base[((unsigned)csr_src[e] << 3) | fp];
        sx += bflo(v);
        sy += bfhi(v);
    }
    float inn = in_norm[node];
    unsigned o = (unsigned)f2bf(sx * inn) | ((unsigned)f2bf(sy * inn) << 16);
    __builtin_nontemporal_store(o, outu + ((size_t)slice * NNODES + node) * 8 + fp);
}

// ---------------- MFMA GEMM (conv layers): relu(A@W+b), optional *out_norm ----------------
// A and Cout are SLICE-MAJOR ushort: buf[(slice*NNODES + row)*16 + f], f in [0,16)

template <int SCALE>
__global__ __launch_bounds__(256) void gemm_mfma_kernel(const unsigned short* __restrict__ A,
                                                        const short8* __restrict__ Bp,
                                                        const float* __restrict__ bias,
                                                        const float* __restrict__ out_norm,
                                                        unsigned short* __restrict__ Cout, int nrows) {
    int w = threadIdx.x >> 6, lane = threadIdx.x & 63;
    int m = lane & 15, quad = lane >> 4;
    int row0 = blockIdx.x * 64 + w * 16;

    int arow = min(row0 + m, nrows - 1);
    short8 afrag[4];
#pragma unroll
    for (int s = 0; s < 4; s++)
        afrag[s] = *(const short8*)(A + ((size_t)(2 * s + (quad >> 1)) * NNODES + arow) * 16 + (quad & 1) * 8);

    int baseRow = row0 + quad * 4;
    float nrm[4];
    if (SCALE) {
#pragma unroll
        for (int r = 0; r < 4; r++) nrm[r] = out_norm[min(baseRow + r, nrows - 1)];
    }

#pragma unroll
    for (int c = 0; c < 8; c++) {
        f32x4 acc = {0.f, 0.f, 0.f, 0.f};
#pragma unroll
        for (int s = 0; s < 4; s++) {
            short8 b = Bp[(c * 4 + s) * 64 + lane];
            acc = __builtin_amdgcn_mfma_f32_16x16x32_bf16(afrag[s], b, acc, 0, 0, 0);
        }
        float bc = bias[c * 16 + m];
#pragma unroll
        for (int r = 0; r < 4; r++) {
            int row = baseRow + r;
            if (row < nrows) {
                float v = fmaxf(acc[r] + bc, 0.f);
                if (SCALE) v *= nrm[r];
                // feat = c*16+m -> slice = c, within = m
                Cout[((size_t)c * NNODES + row) * 16 + m] = f2bf(v);
            }
        }
    }
}

// ---------------- fused MLP head: sigmoid(relu(A@Wm1+bm1)@Wm2+bm2) ----------------
// A is SLICE-MAJOR; output row-major f32

__global__ __launch_bounds__(256) void mlp_fused_kernel(const unsigned short* __restrict__ A,
                                                        const short8* __restrict__ Bp1,
                                                        const float* __restrict__ bm1,
                                                        const short8* __restrict__ Bp2,
                                                        const float* __restrict__ bm2,
                                                        float* __restrict__ out, int nrows) {
    __shared__ unsigned short h3[4][16][136];   // +8 pad: break bank conflicts
    int w = threadIdx.x >> 6, lane = threadIdx.x & 63;
    int m = lane & 15, quad = lane >> 4;
    int row0 = blockIdx.x * 64 + w * 16;

    int arow = min(row0 + m, nrows - 1);
    short8 afrag[4];
#pragma unroll
    for (int s = 0; s < 4; s++)
        afrag[s] = *(const short8*)(A + ((size_t)(2 * s + (quad >> 1)) * NNODES + arow) * 16 + (quad & 1) * 8);

#pragma unroll
    for (int c = 0; c < 8; c++) {
        f32x4 acc = {0.f, 0.f, 0.f, 0.f};
#pragma unroll
        for (int s = 0; s < 4; s++) {
            short8 b = Bp1[(c * 4 + s) * 64 + lane];
            acc = __builtin_amdgcn_mfma_f32_16x16x32_bf16(afrag[s], b, acc, 0, 0, 0);
        }
        float bc = bm1[c * 16 + m];
#pragma unroll
        for (int r = 0; r < 4; r++)
            h3[w][quad * 4 + r][c * 16 + m] = f2bf(fmaxf(acc[r] + bc, 0.f));
    }
    __syncthreads();

    short8 a2[4];
#pragma unroll
    for (int s = 0; s < 4; s++)
        a2[s] = *(const short8*)(&h3[w][m][s * 32 + quad * 8]);

    int baseRow = row0 + quad * 4;
#pragma unroll
    for (int c2 = 0; c2 < 4; c2++) {
        f32x4 acc = {0.f, 0.f, 0.f, 0.f};
#pragma unroll
        for (int s = 0; s < 4; s++) {
            short8 b = Bp2[(c2 * 4 + s) * 64 + lane];
            acc = __builtin_amdgcn_mfma_f32_16x16x32_bf16(a2[s], b, acc, 0, 0, 0);
        }
        float bc = bm2[c2 * 16 + m];
#pragma unroll
        for (int r = 0; r < 4; r++) {
            int row = baseRow + r;
            if (row < nrows)
                out[(size_t)row * 64 + c2 * 16 + m] = 1.f / (1.f + __expf(-(acc[r] + bc)));
        }
    }
}

// ---------------- launch ----------------

extern "C" void kernel_launch(void* const* d_in, const int* in_sizes, int n_in,
                              void* d_out, int out_size, void* d_ws, size_t ws_size,
                              hipStream_t stream) {
    const float* x   = (const float*)d_in[0];
    const int* src   = (const int*)d_in[1];
    const int* dst   = (const int*)d_in[2];
    const float* W1  = (const float*)d_in[3];
    const float* b1  = (const float*)d_in[4];
    const float* W2  = (const float*)d_in[5];
    const float* b2  = (const float*)d_in[6];
    const float* Wm1 = (const float*)d_in[7];
    const float* bm1 = (const float*)d_in[8];
    const float* Wm2 = (const float*)d_in[9];
    const float* bm2 = (const float*)d_in[10];
    float* out = (float*)d_out;

    char* w = (char*)d_ws;
    int* dcur          = (int*)w;   w += (size_t)(NB + 4) * 4;
    int* scur          = (int*)w;   w += (size_t)(NB + 4) * 4;
    float* out_norm    = (float*)w; w += (size_t)NNODES * 4;
    float* in_norm     = (float*)w; w += (size_t)NNODES * 4;
    int2* row_span     = (int2*)w;  w += (size_t)NNODES * 8;
    int* csr_src       = (int*)w;   w += (size_t)NB * CAP * 4;
    unsigned* epk      = (unsigned*)w; w += (size_t)NB * CAP * 4;
    unsigned short* esl= (unsigned short*)w; w += (size_t)NB * CAP * 2;
    short8* Wp         = (short8*)w; w += (size_t)7168 * 16;
    unsigned* bufX     = (unsigned*)w; w += (size_t)NNODES * 64 * 4;
    unsigned* bufY     = (unsigned*)w; w += (size_t)NNODES * 64 * 4;

    init_cursors_kernel<<<1, 256, 0, stream>>>(dcur, scur);
    dual_bin_kernel<<<(NEDGES + T2 - 1) / T2, 256, 0, stream>>>(src, dst, dcur, scur, epk, esl);
    src_hist_kernel<<<NB, 512, 0, stream>>>(esl, scur, out_norm);
    bucket_csr_kernel<<<NB, 512, 0, stream>>>(epk, dcur, row_span, in_norm, csr_src);
    scale_to_bf16_kernel<<<(NNODES * 32 + 255) / 256, 256, 0, stream>>>(x, out_norm, (uint2*)bufX);
    pack_all_kernel<<<28, 256, 0, stream>>>(W1, W2, Wm1, Wm2, Wp);

    const int aggGrid = (NNODES / 32) * NSLICE;   // 3125 node-groups x 8 slices = 25000 blocks
    const int gemmGrid = (NNODES + 63) / 64;

    aggregate_kernel<<<aggGrid, 256, 0, stream>>>(bufX, row_span, csr_src, in_norm, bufY);
    gemm_mfma_kernel<1><<<gemmGrid, 256, 0, stream>>>((const unsigned short*)bufY, Wp, b1, out_norm,
                                                      (unsigned short*)bufX, NNODES);
    aggregate_kernel<<<aggGrid, 256, 0, stream>>>(bufX, row_span, csr_src, in_norm, bufY);
    gemm_mfma_kernel<0><<<gemmGrid, 256, 0, stream>>>((const unsigned short*)bufY, Wp + 2048, b2, out_norm,
                                                      (unsigned short*)bufX, NNODES);
    mlp_fused_kernel<<<gemmGrid, 256, 0, stream>>>((const unsigned short*)bufX, Wp + 4096, bm1,
                                                   Wp + 6144, bm2, out, NNODES);
}

// Round 6
// 569.743 us; speedup vs baseline: 2.4517x; 1.1843x over previous
//
#include <hip/hip_runtime.h>
#include <math.h>

#define NNODES 100000
#define NEDGES 3200000
#define F 128
#define NPB 512
#define NB ((NNODES + NPB - 1) / NPB)   // 196 buckets
#define CAP 20480                        // slots per bucket (mean 16326, 32 sigma margin)
#define T2 8192
#define NKEY (NPB * 16)                  // (dst-local 9b) x (src-range 4b) counting-sort keys

typedef __attribute__((ext_vector_type(8))) short short8;
typedef __attribute__((ext_vector_type(4))) float f32x4;

__device__ __forceinline__ unsigned short f2bf(float f) {
    unsigned u = __float_as_uint(f);
    unsigned r = u + 0x7fff + ((u >> 16) & 1);
    return (unsigned short)(r >> 16);
}
__device__ __forceinline__ float bflo(unsigned u) { return __uint_as_float(u << 16); }
__device__ __forceinline__ float bfhi(unsigned u) { return __uint_as_float(u & 0xffff0000u); }

// ---------------- cursor init (CAP-strided bucket bases) ----------------

__global__ void init_cursors_kernel(int* __restrict__ dcur, int* __restrict__ scur) {
    int b = blockIdx.x * 256 + threadIdx.x;
    if (b < NB) { dcur[b] = b * CAP; scur[b] = b * CAP; }
}

// ---------------- dual binning: one edge read -> dst-keyed + src-keyed bins ----------------

__global__ __launch_bounds__(256) void dual_bin_kernel(const int* __restrict__ src,
                                                       const int* __restrict__ dst,
                                                       int* __restrict__ dcur,
                                                       int* __restrict__ scur,
                                                       unsigned* __restrict__ epk,
                                                       unsigned short* __restrict__ esl) {
    __shared__ unsigned pk[T2];
    __shared__ unsigned short sl[T2];
    __shared__ unsigned char db[T2], sb[T2];
    __shared__ int dh[NB], dbase[NB], dlc[NB];
    __shared__ int sh[NB], sbase[NB], slc[NB];
    int t = threadIdx.x;
    for (int i = t; i < NB; i += 256) { dh[i] = 0; dlc[i] = 0; sh[i] = 0; slc[i] = 0; }
    __syncthreads();
    int e0 = blockIdx.x * T2;
    int n = min(T2, NEDGES - e0);
    for (int i = t; i < n; i += 256) {
        int s = src[e0 + i], d = dst[e0 + i];
        int bd = d >> 9, bs = s >> 9;
        pk[i] = (unsigned)s | ((unsigned)(d & 511) << 17);
        sl[i] = (unsigned short)(s & 511);
        db[i] = (unsigned char)bd;
        sb[i] = (unsigned char)bs;
        atomicAdd(&dh[bd], 1);
        atomicAdd(&sh[bs], 1);
    }
    __syncthreads();
    for (int b = t; b < NB; b += 256) {
        if (dh[b]) dbase[b] = atomicAdd(&dcur[b], dh[b]);
        if (sh[b]) sbase[b] = atomicAdd(&scur[b], sh[b]);
    }
    __syncthreads();
    for (int i = t; i < n; i += 256) {
        int b = db[i];
        epk[dbase[b] + atomicAdd(&dlc[b], 1)] = pk[i];
    }
    for (int i = t; i < n; i += 256) {
        int b = sb[i];
        esl[sbase[b] + atomicAdd(&slc[b], 1)] = sl[i];
    }
}

// ---------------- out-degree -> out_norm (per-bucket LDS histogram) ----------------

__global__ __launch_bounds__(512) void src_hist_kernel(const unsigned short* __restrict__ esl,
                                                       const int* __restrict__ scur,
                                                       float* __restrict__ out_norm) {
    __shared__ int cnt[NPB];
    int t = threadIdx.x, b = blockIdx.x;
    cnt[t] = 0;
    __syncthreads();
    int e0 = b * CAP, e1 = scur[b];
    for (int i = e0 + t; i < e1; i += 512) atomicAdd(&cnt[esl[i]], 1);
    __syncthreads();
    int node = b * NPB + t;
    if (node < NNODES) out_norm[node] = rsqrtf((float)max(cnt[t], 1));
}

// ---------------- per-bucket fine CSR + in_norm, SRC-RANGE-SORTED rows ----------------
// Counting sort on key = (dst_local<<4) | (src>>13): rows come out with edges grouped by
// 8192-node (2MB) source ranges. All aggregate waves then sweep ranges 0..12 in the same
// order -> instantaneous gather working set ~2-4MB -> L2-resident on every XCD (vs 25.6MB
// random = 62% L2 miss at R0). Thread t == dst_local (16 keys per thread).

__global__ __launch_bounds__(512) void bucket_csr_kernel(const unsigned* __restrict__ epk,
                                                         const int* __restrict__ dcur,
                                                         int2* __restrict__ row_span,
                                                         float* __restrict__ in_norm,
                                                         int* __restrict__ csr_src) {
    __shared__ int hist[NKEY];   // 32KB: per-key counts -> per-key exclusive offsets
    __shared__ int lcur[NKEY];   // 32KB: scatter cursors
    __shared__ int psum[NPB];    // block scan of per-thread chunk totals
    int t = threadIdx.x, b = blockIdx.x;
    for (int i = t; i < NKEY; i += 512) { hist[i] = 0; lcur[i] = 0; }
    __syncthreads();
    int e0 = b * CAP, e1 = dcur[b];
    for (int i = e0 + t; i < e1; i += 512) {
        unsigned p = epk[i];
        int key = (int)((p >> 17) << 4) | (int)((p & 0x1FFFF) >> 13);
        atomicAdd(&hist[key], 1);
    }
    __syncthreads();
    // local serial scan: thread t owns keys [t*16, t*16+16)  (== dst_local t)
    int base_ = t << 4;
    int tot = 0;
#pragma unroll
    for (int j = 0; j < 16; j++) {
        int h = hist[base_ + j];
        hist[base_ + j] = tot;      // chunk-exclusive
        tot += h;
    }
    psum[t] = tot;
    __syncthreads();
    for (int d = 1; d < NPB; d <<= 1) {
        int u = (t >= d) ? psum[t - d] : 0;
        __syncthreads();
        psum[t] += u;
        __syncthreads();
    }
    int excl = psum[t] - tot;       // row start offset within bucket
    int node = b * NPB + t;
    if (node < NNODES) {
        row_span[node] = make_int2(e0 + excl, e0 + excl + tot);
        in_norm[node] = rsqrtf((float)max(tot, 1));
    }
#pragma unroll
    for (int j = 0; j < 16; j++) hist[base_ + j] += excl;   // bucket-global exclusive
    __syncthreads();
    for (int i = e0 + t; i < e1; i += 512) {
        unsigned p = epk[i];
        int key = (int)((p >> 17) << 4) | (int)((p & 0x1FFFF) >> 13);
        csr_src[e0 + hist[key] + atomicAdd(&lcur[key], 1)] = (int)(p & 0x1FFFF);
    }
}

// ---------------- x * out_norm -> bf16 (linear row-major pairs) ----------------

__global__ __launch_bounds__(256) void scale_to_bf16_kernel(const float* __restrict__ x,
                                                            const float* __restrict__ out_norm,
                                                            uint2* __restrict__ hs) {
    int tid = blockIdx.x * 256 + threadIdx.x;
    if (tid >= NNODES * 32) return;
    int row = tid >> 5, q = tid & 31;
    float nrm = out_norm[row];
    float4 v = *(const float4*)(x + (size_t)row * F + q * 4);
    uint2 o;
    o.x = (unsigned)f2bf(v.x * nrm) | ((unsigned)f2bf(v.y * nrm) << 16);
    o.y = (unsigned)f2bf(v.z * nrm) | ((unsigned)f2bf(v.w * nrm) << 16);
    hs[(size_t)row * 32 + q] = o;
}

// ---------------- pack all 4 weight matrices into MFMA B-fragments ----------------
// Bp[(c*4+s)*64+lane] = W[s*32+(lane>>4)*8+j][c*16+(lane&15)]

__global__ void pack_all_kernel(const float* __restrict__ W1, const float* __restrict__ W2,
                                const float* __restrict__ Wm1, const float* __restrict__ Wm2,
                                short8* __restrict__ Wp) {
    int idx = blockIdx.x * 256 + threadIdx.x;
    if (idx >= 7168) return;
    const float* W; int ncol, base;
    if (idx < 2048)      { W = W1;  ncol = 128; base = 0; }
    else if (idx < 4096) { W = W2;  ncol = 128; base = 2048; }
    else if (idx < 6144) { W = Wm1; ncol = 128; base = 4096; }
    else                 { W = Wm2; ncol = 64;  base = 6144; }
    int li = idx - base;
    int lane = li & 63, s = (li >> 6) & 3, c = li >> 8;
    int nn = c * 16 + (lane & 15);
    int k0 = s * 32 + (lane >> 4) * 8;
    short8 v;
#pragma unroll
    for (int j = 0; j < 8; j++) v[j] = (short)f2bf(W[(size_t)(k0 + j) * ncol + nn]);
    Wp[idx] = v;
}

// ---------------- aggregation: one wave per node, 8 gathers in flight ----------------
// lane l holds feats (2l, 2l+1) as one uint (2 bf16); fp32 accumulate. Row-major hs:
// 256B coherent gather/instr (4 segments), wave-uniform csr reads (1 segment) — the
// segment-optimal pattern (R5 post-mortem). Edges arrive src-range-sorted, so the gather
// stream sweeps 2MB ranges in order -> L2-resident working set.

__global__ __launch_bounds__(256) void aggregate_kernel(const unsigned* __restrict__ hs,
                                                        const int2* __restrict__ row_span,
                                                        const int* __restrict__ csr_src,
                                                        const float* __restrict__ in_norm,
                                                        unsigned* __restrict__ outv) {
    int wave = threadIdx.x >> 6;
    int lane = threadIdx.x & 63;
    int node = blockIdx.x * 4 + wave;
    if (node >= NNODES) return;
    int2 sp = row_span[node];
    int beg = sp.x, end = sp.y;
    float ax = 0.f, ay = 0.f;
    int j = beg;
    for (; j + 8 <= end; j += 8) {
        int s0 = csr_src[j],     s1 = csr_src[j + 1], s2 = csr_src[j + 2], s3 = csr_src[j + 3];
        int s4 = csr_src[j + 4], s5 = csr_src[j + 5], s6 = csr_src[j + 6], s7 = csr_src[j + 7];
        unsigned u0 = hs[(size_t)s0 * 64 + lane];
        unsigned u1 = hs[(size_t)s1 * 64 + lane];
        unsigned u2 = hs[(size_t)s2 * 64 + lane];
        unsigned u3 = hs[(size_t)s3 * 64 + lane];
        unsigned u4 = hs[(size_t)s4 * 64 + lane];
        unsigned u5 = hs[(size_t)s5 * 64 + lane];
        unsigned u6 = hs[(size_t)s6 * 64 + lane];
        unsigned u7 = hs[(size_t)s7 * 64 + lane];
        ax += bflo(u0) + bflo(u1) + bflo(u2) + bflo(u3)
            + bflo(u4) + bflo(u5) + bflo(u6) + bflo(u7);
        ay += bfhi(u0) + bfhi(u1) + bfhi(u2) + bfhi(u3)
            + bfhi(u4) + bfhi(u5) + bfhi(u6) + bfhi(u7);
    }
    for (; j < end; j++) {
        unsigned u0 = hs[(size_t)csr_src[j] * 64 + lane];
        ax += bflo(u0);
        ay += bfhi(u0);
    }
    float inn = in_norm[node];
    outv[(size_t)node * 64 + lane] =
        (unsigned)f2bf(ax * inn) | ((unsigned)f2bf(ay * inn) << 16);
}

// ---------------- MFMA GEMM (conv layers): relu(A@W+b), optional *out_norm ----------------

template <int SCALE>
__global__ __launch_bounds__(256) void gemm_mfma_kernel(const unsigned short* __restrict__ A,
                                                        const short8* __restrict__ Bp,
                                                        const float* __restrict__ bias,
                                                        const float* __restrict__ out_norm,
                                                        unsigned short* __restrict__ Cout, int nrows) {
    int w = threadIdx.x >> 6, lane = threadIdx.x & 63;
    int m = lane & 15, quad = lane >> 4;
    int row0 = blockIdx.x * 64 + w * 16;

    int arow = min(row0 + m, nrows - 1);
    short8 afrag[4];
#pragma unroll
    for (int s = 0; s < 4; s++)
        afrag[s] = *(const short8*)(A + (size_t)arow * F + s * 32 + quad * 8);

    int baseRow = row0 + quad * 4;
    float nrm[4];
    if (SCALE) {
#pragma unroll
        for (int r = 0; r < 4; r++) nrm[r] = out_norm[min(baseRow + r, nrows - 1)];
    }

#pragma unroll
    for (int c = 0; c < 8; c++) {
        f32x4 acc = {0.f, 0.f, 0.f, 0.f};
#pragma unroll
        for (int s = 0; s < 4; s++) {
            short8 b = Bp[(c * 4 + s) * 64 + lane];
            acc = __builtin_amdgcn_mfma_f32_16x16x32_bf16(afrag[s], b, acc, 0, 0, 0);
        }
        float bc = bias[c * 16 + m];
#pragma unroll
        for (int r = 0; r < 4; r++) {
            int row = baseRow + r;
            if (row < nrows) {
                float v = fmaxf(acc[r] + bc, 0.f);
                if (SCALE) v *= nrm[r];
                Cout[(size_t)row * F + c * 16 + m] = f2bf(v);
            }
        }
    }
}

// ---------------- fused MLP head: sigmoid(relu(A@Wm1+bm1)@Wm2+bm2) ----------------

__global__ __launch_bounds__(256) void mlp_fused_kernel(const unsigned short* __restrict__ A,
                                                        const short8* __restrict__ Bp1,
                                                        const float* __restrict__ bm1,
                                                        const short8* __restrict__ Bp2,
                                                        const float* __restrict__ bm2,
                                                        float* __restrict__ out, int nrows) {
    __shared__ unsigned short h3[4][16][136];   // +8 pad: break bank conflicts
    int w = threadIdx.x >> 6, lane = threadIdx.x & 63;
    int m = lane & 15, quad = lane >> 4;
    int row0 = blockIdx.x * 64 + w * 16;

    int arow = min(row0 + m, nrows - 1);
    short8 afrag[4];
#pragma unroll
    for (int s = 0; s < 4; s++)
        afrag[s] = *(const short8*)(A + (size_t)arow * F + s * 32 + quad * 8);

#pragma unroll
    for (int c = 0; c < 8; c++) {
        f32x4 acc = {0.f, 0.f, 0.f, 0.f};
#pragma unroll
        for (int s = 0; s < 4; s++) {
            short8 b = Bp1[(c * 4 + s) * 64 + lane];
            acc = __builtin_amdgcn_mfma_f32_16x16x32_bf16(afrag[s], b, acc, 0, 0, 0);
        }
        float bc = bm1[c * 16 + m];
#pragma unroll
        for (int r = 0; r < 4; r++)
            h3[w][quad * 4 + r][c * 16 + m] = f2bf(fmaxf(acc[r] + bc, 0.f));
    }
    __syncthreads();

    short8 a2[4];
#pragma unroll
    for (int s = 0; s < 4; s++)
        a2[s] = *(const short8*)(&h3[w][m][s * 32 + quad * 8]);

    int baseRow = row0 + quad * 4;
#pragma unroll
    for (int c2 = 0; c2 < 4; c2++) {
        f32x4 acc = {0.f, 0.f, 0.f, 0.f};
#pragma unroll
        for (int s = 0; s < 4; s++) {
            short8 b = Bp2[(c2 * 4 + s) * 64 + lane];
            acc = __builtin_amdgcn_mfma_f32_16x16x32_bf16(a2[s], b, acc, 0, 0, 0);
        }
        float bc = bm2[c2 * 16 + m];
#pragma unroll
        for (int r = 0; r < 4; r++) {
            int row = baseRow + r;
            if (row < nrows)
                out[(size_t)row * 64 + c2 * 16 + m] = 1.f / (1.f + __expf(-(acc[r] + bc)));
        }
    }
}

// ---------------- launch ----------------

extern "C" void kernel_launch(void* const* d_in, const int* in_sizes, int n_in,
                              void* d_out, int out_size, void* d_ws, size_t ws_size,
                              hipStream_t stream) {
    const float* x   = (const float*)d_in[0];
    const int* src   = (const int*)d_in[1];
    const int* dst   = (const int*)d_in[2];
    const float* W1  = (const float*)d_in[3];
    const float* b1  = (const float*)d_in[4];
    const float* W2  = (const float*)d_in[5];
    const float* b2  = (const float*)d_in[6];
    const float* Wm1 = (const float*)d_in[7];
    const float* bm1 = (const float*)d_in[8];
    const float* Wm2 = (const float*)d_in[9];
    const float* bm2 = (const float*)d_in[10];
    float* out = (float*)d_out;

    char* w = (char*)d_ws;
    int* dcur          = (int*)w;   w += (size_t)(NB + 4) * 4;
    int* scur          = (int*)w;   w += (size_t)(NB + 4) * 4;
    float* out_norm    = (float*)w; w += (size_t)NNODES * 4;
    float* in_norm     = (float*)w; w += (size_t)NNODES * 4;
    int2* row_span     = (int2*)w;  w += (size_t)NNODES * 8;
    int* csr_src       = (int*)w;   w += (size_t)NB * CAP * 4;
    unsigned* epk      = (unsigned*)w; w += (size_t)NB * CAP * 4;
    unsigned short* esl= (unsigned short*)w; w += (size_t)NB * CAP * 2;
    short8* Wp         = (short8*)w; w += (size_t)7168 * 16;
    unsigned* bufX     = (unsigned*)w; w += (size_t)NNODES * 64 * 4;
    unsigned* bufY     = (unsigned*)w; w += (size_t)NNODES * 64 * 4;

    init_cursors_kernel<<<1, 256, 0, stream>>>(dcur, scur);
    dual_bin_kernel<<<(NEDGES + T2 - 1) / T2, 256, 0, stream>>>(src, dst, dcur, scur, epk, esl);
    src_hist_kernel<<<NB, 512, 0, stream>>>(esl, scur, out_norm);
    bucket_csr_kernel<<<NB, 512, 0, stream>>>(epk, dcur, row_span, in_norm, csr_src);
    scale_to_bf16_kernel<<<(NNODES * 32 + 255) / 256, 256, 0, stream>>>(x, out_norm, (uint2*)bufX);
    pack_all_kernel<<<28, 256, 0, stream>>>(W1, W2, Wm1, Wm2, Wp);

    const int aggGrid = (NNODES + 3) / 4;
    const int gemmGrid = (NNODES + 63) / 64;

    aggregate_kernel<<<aggGrid, 256, 0, stream>>>(bufX, row_span, csr_src, in_norm, bufY);
    gemm_mfma_kernel<1><<<gemmGrid, 256, 0, stream>>>((const unsigned short*)bufY, Wp, b1, out_norm,
                                                      (unsigned short*)bufX, NNODES);
    aggregate_kernel<<<aggGrid, 256, 0, stream>>>(bufX, row_span, csr_src, in_norm, bufY);
    gemm_mfma_kernel<0><<<gemmGrid, 256, 0, stream>>>((const unsigned short*)bufY, Wp + 2048, b2, out_norm,
                                                      (unsigned short*)bufX, NNODES);
    mlp_fused_kernel<<<gemmGrid, 256, 0, stream>>>((const unsigned short*)bufX, Wp + 4096, bm1,
                                                   Wp + 6144, bm2, out, NNODES);
}